// Round 16
// baseline (76.561 us; speedup 1.0000x reference)
//
#include <hip/hip_runtime.h>
#include <hip/hip_bf16.h>
#include <math.h>

#define IN_F   256
#define OUT_F  64
#define ALPHA  0.2f

// bucket sort params (requires n < 65536 so dst fits in 16 bits; n = 50000)
#define BKT_SHIFT 7
#define BKT_NODES 128
#define BKT_CAP   3072
#define NB_MAX    512
#define CHUNK     4096
#define SLICE_NODES 32        // nodes handled per sort2_edge block (4 blocks/bucket)

typedef __attribute__((ext_vector_type(8))) short short8v;
typedef __attribute__((ext_vector_type(4))) float f32x4;
typedef __attribute__((ext_vector_type(2))) float f32x2;

static __device__ __forceinline__ unsigned short f2bf_rne(float f) {
    unsigned int u = __float_as_uint(f);
    unsigned int lsb = (u >> 16) & 1u;
    u += 0x7FFFu + lsb;
    return (unsigned short)(u >> 16);
}

static __device__ __forceinline__ unsigned int pack_bf2(float lo, float hi) {
    __hip_bfloat162 h = __float22bfloat162_rn(float2{lo, hi});
    return *reinterpret_cast<unsigned int*>(&h);
}

// swizzled Wt index: element (nc, k) lives at nc*256 + (k ^ ((nc&7)<<3))
static __device__ __forceinline__ int wt_idx(int nc, int k) {
    return nc * IN_F + (k ^ ((nc & 7) << 3));
}

// unpack 2 packed bf16 -> f32x2 {lo, hi}
static __device__ __forceinline__ f32x2 bf2_up(unsigned int u) {
    f32x2 r;
    r.x = __uint_as_float(u << 16);
    r.y = __uint_as_float(u & 0xFFFF0000u);
    return r;
}

// DPP cross-lane adds (VALU pipe, no DS traffic). CTRL is compile-time.
template<int CTRL>
static __device__ __forceinline__ float dpp_add(float x) {
    int y = __builtin_amdgcn_update_dpp(0, __float_as_int(x), CTRL, 0xF, 0xF, true);
    return x + __int_as_float(y);
}

// ---------------------------------------------------------------------------
// Wt (swizzled) bf16; block 0 also zeroes bucket_cursor (replaces memset).
// ---------------------------------------------------------------------------
__global__ __launch_bounds__(256)
void transpose_w(const float* __restrict__ W, unsigned short* __restrict__ Wt,
                 int* __restrict__ bucket_cursor, int nb)
{
    if (blockIdx.x == 0) {
        for (int i = threadIdx.x; i < nb; i += 256) bucket_cursor[i] = 0;
    }
    int tid = blockIdx.x * 256 + threadIdx.x;   // 0..32767
    int nc = tid >> 8;
    int k  = tid & 255;
    float v = (nc < 64) ? W[(size_t)k * OUT_F + nc]
                        : W[(size_t)(IN_F + k) * OUT_F + (nc - 64)];
    Wt[wt_idx(nc, k)] = f2bf_rne(v);
}

// ---------------------------------------------------------------------------
// Fused independent phases, block-partitioned:
//   blocks [0, gemmBlocks):       MFMA GEMM, Wt staged to 64KB LDS (the
//     LDS broadcast is essential: L2-serving regressed 19->54 us, round 14)
//   blocks [gemmBlocks, total):   sort pass1 -> bucket binning of edges
// ---------------------------------------------------------------------------
__global__ __launch_bounds__(512)
void gemm_sort(const float* __restrict__ x, const unsigned short* __restrict__ Wt,
               unsigned short* __restrict__ WhC,
               const int* __restrict__ src, const int* __restrict__ dst,
               int* __restrict__ bucket_cursor, unsigned int* __restrict__ bucket_buf,
               int n, int nb, int E, int gemmBlocks)
{
    __shared__ __align__(16) unsigned char smem[65536];
    const int t = threadIdx.x;

    if ((int)blockIdx.x < gemmBlocks) {
        // ---------------- GEMM path (LDS-staged B) ----------------
        unsigned short* lds_wt = (unsigned short*)smem;
        const int wid  = t >> 6;
        const int lane = t & 63;
        const int r16  = lane & 15;
        const int kq   = lane >> 4;
        const int m0   = blockIdx.x * 128 + wid * 16;

        {
            const uint4* gw = (const uint4*)Wt;
            uint4*       lw = (uint4*)lds_wt;
#pragma unroll
            for (int i = 0; i < 8; ++i)
                lw[t + i * 512] = gw[t + i * 512];
        }

        int arow = m0 + r16;
        if (arow >= n) arow = n - 1;
        const float* xr = &x[(size_t)arow * IN_F + kq * 8];

        float4 araw[16];
#pragma unroll
        for (int ks = 0; ks < 8; ++ks) {
            araw[2 * ks]     = *(const float4*)&xr[ks * 32];
            araw[2 * ks + 1] = *(const float4*)&xr[ks * 32 + 4];
        }
        __syncthreads();

        short8v afrag[8];
#pragma unroll
        for (int ks = 0; ks < 8; ++ks) {
            union { short8v s; unsigned int u[4]; } fr;
            fr.u[0] = pack_bf2(araw[2 * ks].x, araw[2 * ks].y);
            fr.u[1] = pack_bf2(araw[2 * ks].z, araw[2 * ks].w);
            fr.u[2] = pack_bf2(araw[2 * ks + 1].x, araw[2 * ks + 1].y);
            fr.u[3] = pack_bf2(araw[2 * ks + 1].z, araw[2 * ks + 1].w);
            afrag[ks] = fr.s;
        }

        f32x4 acc[8];
#pragma unroll
        for (int nt = 0; nt < 8; ++nt) acc[nt] = (f32x4){0.f, 0.f, 0.f, 0.f};

#pragma unroll
        for (int ks = 0; ks < 8; ++ks) {
#pragma unroll
            for (int nt = 0; nt < 8; ++nt) {
                int nc = nt * 16 + r16;
                short8v b = *(const short8v*)&lds_wt[wt_idx(nc, ks * 32 + kq * 8)];
                acc[nt] = __builtin_amdgcn_mfma_f32_16x16x32_bf16(afrag[ks], b, acc[nt], 0, 0, 0);
            }
        }

        const int rbase = m0 + kq * 4;
#pragma unroll
        for (int nt = 0; nt < 8; ++nt) {
            int colc = nt * 16 + r16;
            int off  = (colc < 64) ? (colc + 64) : (colc - 64);
#pragma unroll
            for (int r = 0; r < 4; ++r) {
                int gr = rbase + r;
                if (gr < n) WhC[(size_t)gr * 128 + off] = f2bf_rne(acc[nt][r]);
            }
        }
    } else {
        // ---------------- sort pass 1 path (512 threads, 8 edges/thread) ----
        int* cnt   = (int*)smem;                    // NB_MAX ints
        int* off   = cnt + NB_MAX;                  // NB_MAX ints
        int* gbase = off + NB_MAX;                  // NB_MAX ints
        int* wsum  = gbase + NB_MAX;                // 16 ints
        unsigned int*   stag = (unsigned int*)(wsum + 16);      // CHUNK uints
        unsigned short* bkt  = (unsigned short*)(stag + CHUNK); // CHUNK ushorts

        const int bid = (int)blockIdx.x - gemmBlocks;
        const int e0  = bid * CHUNK;

        for (int i = t; i < nb; i += 512) cnt[i] = 0;
        __syncthreads();

        int myb[8]; int myr[8]; unsigned int myp[8];
#pragma unroll
        for (int l = 0; l < 8; ++l) {
            int e = e0 + l * 512 + t;
            if (e < E) {
                int s = src[e], d = dst[e];
                int b = s >> BKT_SHIFT;
                myb[l] = b;
                myp[l] = ((unsigned int)(s & (BKT_NODES - 1)) << 16) | (unsigned int)d;
                myr[l] = atomicAdd(&cnt[b], 1);
            } else myb[l] = -1;
        }
        __syncthreads();

        {
            int v    = (t < nb) ? cnt[t] : 0;
            int lane = t & 63, w = t >> 6;     // 8 waves
            int xv = v;
#pragma unroll
            for (int o = 1; o < 64; o <<= 1) {
                int y = __shfl_up(xv, o);
                if (lane >= o) xv += y;
            }
            if (lane == 63) wsum[w] = xv;
            __syncthreads();
            if (t == 0) {
                int s = 0;
#pragma unroll
                for (int k = 0; k < 8; ++k) { int tv = wsum[k]; wsum[k] = s; s += tv; }
                wsum[8] = s;
            }
            __syncthreads();
            int excl = xv - v + wsum[w];
            if (t < nb) off[t] = excl;
        }
        __syncthreads();

        for (int i = t; i < nb; i += 512) {
            int c = cnt[i];
            gbase[i] = c ? atomicAdd(&bucket_cursor[i], c) : 0;
        }
        __syncthreads();

#pragma unroll
        for (int l = 0; l < 8; ++l) {
            if (myb[l] >= 0) {
                int slot = off[myb[l]] + myr[l];
                stag[slot] = myp[l];
                bkt[slot]  = (unsigned short)myb[l];
            }
        }
        __syncthreads();

        const int tot = wsum[8];
        for (int slot = t; slot < tot; slot += 512) {
            int b   = bkt[slot];
            int pos = gbase[b] + (slot - off[b]);
            if (pos < BKT_CAP)
                bucket_buf[(size_t)b * BKT_CAP + pos] = stag[slot];
        }
    }
}

// ---------------------------------------------------------------------------
// Fused sort-pass2 + edge kernel. One block per 32-node slice of a bucket
// (4 blocks/bucket). Block filters its slice's edges from bucket_buf into an
// LDS dst list (local CSR), then runs the per-node edge loop with dst served
// from LDS. No global CSR arrays.
// ---------------------------------------------------------------------------
__global__ __launch_bounds__(256)
void sort2_edge(const unsigned int* __restrict__ bucket_buf,
                const int* __restrict__ bucket_cursor,
                const unsigned short* __restrict__ WhC,
                const float* __restrict__ a,
                float* __restrict__ out, int n)
{
    __shared__ unsigned short sdst[BKT_CAP];        // 6 KB
    __shared__ int ncnt[SLICE_NODES];
    __shared__ int noff[SLICE_NODES + 1];
    __shared__ int noffw[SLICE_NODES];

    const int blk   = blockIdx.x;
    const int b     = blk >> 2;            // bucket
    const int slice = blk & 3;             // quarter 0..3
    const int t     = threadIdx.x;

    int cntE = bucket_cursor[b];
    if (cntE > BKT_CAP) cntE = BKT_CAP;
    const unsigned int* bb = &bucket_buf[(size_t)b * BKT_CAP];

    if (t < SLICE_NODES) ncnt[t] = 0;
    __syncthreads();

    // count this slice's edges per local node
    for (int i = t; i < cntE; i += 256) {
        int sl = (bb[i] >> 16) & (BKT_NODES - 1);
        if ((sl >> 5) == slice) atomicAdd(&ncnt[sl & (SLICE_NODES - 1)], 1);
    }
    __syncthreads();

    // scan 32 counts (lanes 0..31 of wave 0)
    if (t < 32) {
        int v = ncnt[t];
        int x = v;
#pragma unroll
        for (int o = 1; o < 32; o <<= 1) {
            int y = __shfl_up(x, o);
            if (t >= o) x += y;
        }
        noff[t]  = x - v;
        noffw[t] = x - v;
        if (t == 31) noff[SLICE_NODES] = x;
    }
    __syncthreads();

    // scatter this slice's edges into LDS (local order by node)
    for (int i = t; i < cntE; i += 256) {
        unsigned int p = bb[i];
        int sl = (p >> 16) & (BKT_NODES - 1);
        if ((sl >> 5) == slice) {
            int pos = atomicAdd(&noffw[sl & (SLICE_NODES - 1)], 1);
            sdst[pos] = (unsigned short)(p & 0xFFFFu);
        }
    }
    __syncthreads();

    // ---- edge phase: wave w handles local nodes w, w+4, ... (8 nodes) ----
    const int wid  = t >> 6;
    const int lane = t & 63;
    const int g    = lane >> 3;
    const int l8   = lane & 7;
    const int fo   = l8 * 8;

    for (int ln = wid; ln < SLICE_NODES; ln += 4) {
        const int node = b * BKT_NODES + slice * SLICE_NODES + ln;
        if (node >= n) continue;            // wave-uniform

        const int beg = noff[ln];
        const int end = noff[ln + 1];

        f32x2 wsrc[4], av2[4];
        {
            uint4 raw = *(const uint4*)&WhC[(size_t)node * 128 + 64 + fo];
            const unsigned int u[4] = {raw.x, raw.y, raw.z, raw.w};
#pragma unroll
            for (int q = 0; q < 4; ++q) wsrc[q] = bf2_up(u[q]);
            float4 a0 = *(const float4*)&a[fo];
            float4 a1 = *(const float4*)&a[fo + 4];
            av2[0] = (f32x2){a0.x, a0.y}; av2[1] = (f32x2){a0.z, a0.w};
            av2[2] = (f32x2){a1.x, a1.y}; av2[3] = (f32x2){a1.z, a1.w};
        }

        float sumv = 0.f;
        f32x2 acc2[4];
#pragma unroll
        for (int q = 0; q < 4; ++q) acc2[q] = (f32x2){0.f, 0.f};

        int e = beg + g;
        for (; e + 8 < end; e += 16) {
            int d0 = (int)sdst[e] << 7;
            int d1 = (int)sdst[e + 8] << 7;
            uint4 rj0 = *(const uint4*)&WhC[(size_t)d0 + fo];
            uint4 rj1 = *(const uint4*)&WhC[(size_t)d1 + fo];
            uint4 ri0 = *(const uint4*)&WhC[(size_t)d0 + 64 + fo];
            uint4 ri1 = *(const uint4*)&WhC[(size_t)d1 + 64 + fo];
            const unsigned int uj0[4] = {rj0.x, rj0.y, rj0.z, rj0.w};
            const unsigned int uj1[4] = {rj1.x, rj1.y, rj1.z, rj1.w};
            f32x2 p0v = (f32x2){0.f, 0.f}, p1v = (f32x2){0.f, 0.f};
#pragma unroll
            for (int q = 0; q < 4; ++q) {
                f32x2 z0 = bf2_up(uj0[q]) + wsrc[q];
                f32x2 z1 = bf2_up(uj1[q]) + wsrc[q];
                f32x2 t0 = __builtin_elementwise_max(z0, z0 * ALPHA);
                f32x2 t1 = __builtin_elementwise_max(z1, z1 * ALPHA);
                p0v += av2[q] * t0;
                p1v += av2[q] * t1;
            }
            float p0 = p0v.x + p0v.y;
            float p1 = p1v.x + p1v.y;
            p0 = dpp_add<0xB1>(p0);  p1 = dpp_add<0xB1>(p1);
            p0 = dpp_add<0x4E>(p0);  p1 = dpp_add<0x4E>(p1);
            p0 += __shfl_xor(p0, 4); p1 += __shfl_xor(p1, 4);
            float ev0 = __expf(p0);
            float ev1 = __expf(p1);
            sumv += ev0 + ev1;
            const unsigned int ui0[4] = {ri0.x, ri0.y, ri0.z, ri0.w};
            const unsigned int ui1[4] = {ri1.x, ri1.y, ri1.z, ri1.w};
            f32x2 e0v = (f32x2){ev0, ev0};
            f32x2 e1v = (f32x2){ev1, ev1};
#pragma unroll
            for (int q = 0; q < 4; ++q) {
                acc2[q] += e0v * bf2_up(ui0[q]);
                acc2[q] += e1v * bf2_up(ui1[q]);
            }
        }
        if (e < end) {
            int d0 = (int)sdst[e] << 7;
            uint4 rj0 = *(const uint4*)&WhC[(size_t)d0 + fo];
            uint4 ri0 = *(const uint4*)&WhC[(size_t)d0 + 64 + fo];
            const unsigned int uj0[4] = {rj0.x, rj0.y, rj0.z, rj0.w};
            f32x2 p0v = (f32x2){0.f, 0.f};
#pragma unroll
            for (int q = 0; q < 4; ++q) {
                f32x2 z0 = bf2_up(uj0[q]) + wsrc[q];
                f32x2 t0 = __builtin_elementwise_max(z0, z0 * ALPHA);
                p0v += av2[q] * t0;
            }
            float p0 = p0v.x + p0v.y;
            p0 = dpp_add<0xB1>(p0);
            p0 = dpp_add<0x4E>(p0);
            p0 += __shfl_xor(p0, 4);
            float ev0 = __expf(p0);
            sumv += ev0;
            const unsigned int ui0[4] = {ri0.x, ri0.y, ri0.z, ri0.w};
            f32x2 e0v = (f32x2){ev0, ev0};
#pragma unroll
            for (int q = 0; q < 4; ++q) acc2[q] += e0v * bf2_up(ui0[q]);
        }

        float acc[8];
#pragma unroll
        for (int q = 0; q < 4; ++q) { acc[2 * q] = acc2[q].x; acc[2 * q + 1] = acc2[q].y; }
        sumv = dpp_add<0x128>(sumv);
        sumv += __shfl_xor(sumv, 16);
        sumv += __shfl_xor(sumv, 32);
#pragma unroll
        for (int j = 0; j < 8; ++j) {
            acc[j] = dpp_add<0x128>(acc[j]);
            acc[j] += __shfl_xor(acc[j], 16);
            acc[j] += __shfl_xor(acc[j], 32);
        }

        if (g == 0) {
            float rinv = __builtin_amdgcn_rcpf(sumv);
            float o[8];
#pragma unroll
            for (int j = 0; j < 8; ++j) {
                float v = acc[j] * rinv;
                o[j] = v > 0.f ? v : (__expf(v) - 1.0f);
            }
            float* op = &out[(size_t)node * OUT_F + fo];
            *(float4*)op       = make_float4(o[0], o[1], o[2], o[3]);
            *(float4*)(op + 4) = make_float4(o[4], o[5], o[6], o[7]);
        }
    }
}

// ---------------------------------------------------------------------------
extern "C" void kernel_launch(void* const* d_in, const int* in_sizes, int n_in,
                              void* d_out, int out_size, void* d_ws, size_t ws_size,
                              hipStream_t stream)
{
    const float* x    = (const float*)d_in[0];
    const float* W    = (const float*)d_in[1];
    const float* a    = (const float*)d_in[2];
    const int*   edge = (const int*)d_in[3];

    const int n = in_sizes[0] / IN_F;      // 50000
    const int E = in_sizes[3] / 2;         // 800000
    const int* srcI = edge;
    const int* dstI = edge + E;
    const int nb = (n + BKT_NODES - 1) >> BKT_SHIFT;   // 391

    // workspace layout
    char* ws = (char*)d_ws;
    unsigned short* WhC = (unsigned short*)ws;  ws += (size_t)n * 128 * 2;
    unsigned short* Wt  = (unsigned short*)ws;  ws += (size_t)128 * IN_F * 2;
    unsigned int* bucket_buf = (unsigned int*)ws; ws += (size_t)nb * BKT_CAP * 4;
    int*   bucket_cursor= (int*)ws;             ws += (size_t)nb * 4;

    float* out = (float*)d_out;

    // 1) W transpose->bf16 (pre-swizzled) + bucket_cursor zeroing
    transpose_w<<<128, 256, 0, stream>>>(W, Wt, bucket_cursor, nb);

    // 2) fused GEMM (LDS-staged, 128 rows/block) + sort pass1
    int gblocks  = (n + 127) / 128;                  // 391
    int p1blocks = (E + CHUNK - 1) / CHUNK;          // 196
    gemm_sort<<<gblocks + p1blocks, 512, 0, stream>>>(
        x, Wt, WhC, srcI, dstI, bucket_cursor, bucket_buf, n, nb, E, gblocks);

    // 3) fused sort pass2 + edge phase (4 blocks per bucket)
    sort2_edge<<<nb * 4, 256, 0, stream>>>(bucket_buf, bucket_cursor,
                                           WhC, a, out, n);
}

// Round 17
// 65.830 us; speedup vs baseline: 1.1630x; 1.1630x over previous
//
#include <hip/hip_runtime.h>
#include <hip/hip_bf16.h>
#include <math.h>

#define IN_F   256
#define OUT_F  64
#define ALPHA  0.2f

// bucket sort params (requires n < 65536 so dst fits in 16 bits; n = 50000)
#define BKT_SHIFT 7
#define BKT_NODES 128
#define BKT_CAP   3072
#define NB_MAX    512
#define CHUNK     4096

typedef __attribute__((ext_vector_type(8))) short short8v;
typedef __attribute__((ext_vector_type(4))) float f32x4;
typedef __attribute__((ext_vector_type(2))) float f32x2;

static __device__ __forceinline__ unsigned short f2bf_rne(float f) {
    unsigned int u = __float_as_uint(f);
    unsigned int lsb = (u >> 16) & 1u;
    u += 0x7FFFu + lsb;
    return (unsigned short)(u >> 16);
}

static __device__ __forceinline__ unsigned int pack_bf2(float lo, float hi) {
    __hip_bfloat162 h = __float22bfloat162_rn(float2{lo, hi});
    return *reinterpret_cast<unsigned int*>(&h);
}

// swizzled Wt index: element (nc, k) lives at nc*256 + (k ^ ((nc&7)<<3))
static __device__ __forceinline__ int wt_idx(int nc, int k) {
    return nc * IN_F + (k ^ ((nc & 7) << 3));
}

// unpack 2 packed bf16 -> f32x2 {lo, hi}
static __device__ __forceinline__ f32x2 bf2_up(unsigned int u) {
    f32x2 r;
    r.x = __uint_as_float(u << 16);
    r.y = __uint_as_float(u & 0xFFFF0000u);
    return r;
}

// DPP cross-lane adds (VALU pipe). CTRL compile-time.
// xor1: quad_perm [1,0,3,2]=0xB1 ; xor2: quad_perm [2,3,0,1]=0x4E ;
// xor8 within 16-lane row: row_ror:8 = 0x128.
template<int CTRL>
static __device__ __forceinline__ float dpp_add(float x) {
    int y = __builtin_amdgcn_update_dpp(0, __float_as_int(x), CTRL, 0xF, 0xF, true);
    return x + __int_as_float(y);
}

// ds_swizzle xor-add (single DS instr, 32-lane local; MASK<=31).
// BitMode offset = xor<<10 | or<<5 | and(0x1F).
template<int MASK>
static __device__ __forceinline__ float swz_add(float x) {
    int y = __builtin_amdgcn_ds_swizzle(__float_as_int(x), (MASK << 10) | 0x1F);
    return x + __int_as_float(y);
}

// ---------------------------------------------------------------------------
// Wt (swizzled) bf16; block 0 also zeroes bucket_cursor (replaces memset).
// ---------------------------------------------------------------------------
__global__ __launch_bounds__(256)
void transpose_w(const float* __restrict__ W, unsigned short* __restrict__ Wt,
                 int* __restrict__ bucket_cursor, int nb)
{
    if (blockIdx.x == 0) {
        for (int i = threadIdx.x; i < nb; i += 256) bucket_cursor[i] = 0;
    }
    int tid = blockIdx.x * 256 + threadIdx.x;   // 0..32767
    int nc = tid >> 8;
    int k  = tid & 255;
    float v = (nc < 64) ? W[(size_t)k * OUT_F + nc]
                        : W[(size_t)(IN_F + k) * OUT_F + (nc - 64)];
    Wt[wt_idx(nc, k)] = f2bf_rne(v);
}

// ---------------------------------------------------------------------------
// Fused independent phases, block-partitioned:
//   blocks [0, gemmBlocks):       MFMA GEMM, Wt staged to 64KB LDS (the
//     LDS broadcast is essential: L2-serving regressed 19->54 us, round 14)
//   blocks [gemmBlocks, total):   sort pass1 -> bucket binning of edges
// ---------------------------------------------------------------------------
__global__ __launch_bounds__(512)
void gemm_sort(const float* __restrict__ x, const unsigned short* __restrict__ Wt,
               unsigned short* __restrict__ WhC,
               const int* __restrict__ src, const int* __restrict__ dst,
               int* __restrict__ bucket_cursor, unsigned int* __restrict__ bucket_buf,
               int n, int nb, int E, int gemmBlocks)
{
    __shared__ __align__(16) unsigned char smem[65536];
    const int t = threadIdx.x;

    if ((int)blockIdx.x < gemmBlocks) {
        // ---------------- GEMM path (LDS-staged B) ----------------
        unsigned short* lds_wt = (unsigned short*)smem;
        const int wid  = t >> 6;
        const int lane = t & 63;
        const int r16  = lane & 15;
        const int kq   = lane >> 4;
        const int m0   = blockIdx.x * 128 + wid * 16;

        {
            const uint4* gw = (const uint4*)Wt;
            uint4*       lw = (uint4*)lds_wt;
#pragma unroll
            for (int i = 0; i < 8; ++i)
                lw[t + i * 512] = gw[t + i * 512];
        }

        int arow = m0 + r16;
        if (arow >= n) arow = n - 1;
        const float* xr = &x[(size_t)arow * IN_F + kq * 8];

        float4 araw[16];
#pragma unroll
        for (int ks = 0; ks < 8; ++ks) {
            araw[2 * ks]     = *(const float4*)&xr[ks * 32];
            araw[2 * ks + 1] = *(const float4*)&xr[ks * 32 + 4];
        }
        __syncthreads();

        short8v afrag[8];
#pragma unroll
        for (int ks = 0; ks < 8; ++ks) {
            union { short8v s; unsigned int u[4]; } fr;
            fr.u[0] = pack_bf2(araw[2 * ks].x, araw[2 * ks].y);
            fr.u[1] = pack_bf2(araw[2 * ks].z, araw[2 * ks].w);
            fr.u[2] = pack_bf2(araw[2 * ks + 1].x, araw[2 * ks + 1].y);
            fr.u[3] = pack_bf2(araw[2 * ks + 1].z, araw[2 * ks + 1].w);
            afrag[ks] = fr.s;
        }

        f32x4 acc[8];
#pragma unroll
        for (int nt = 0; nt < 8; ++nt) acc[nt] = (f32x4){0.f, 0.f, 0.f, 0.f};

#pragma unroll
        for (int ks = 0; ks < 8; ++ks) {
#pragma unroll
            for (int nt = 0; nt < 8; ++nt) {
                int nc = nt * 16 + r16;
                short8v b = *(const short8v*)&lds_wt[wt_idx(nc, ks * 32 + kq * 8)];
                acc[nt] = __builtin_amdgcn_mfma_f32_16x16x32_bf16(afrag[ks], b, acc[nt], 0, 0, 0);
            }
        }

        const int rbase = m0 + kq * 4;
#pragma unroll
        for (int nt = 0; nt < 8; ++nt) {
            int colc = nt * 16 + r16;
            int off  = (colc < 64) ? (colc + 64) : (colc - 64);
#pragma unroll
            for (int r = 0; r < 4; ++r) {
                int gr = rbase + r;
                if (gr < n) WhC[(size_t)gr * 128 + off] = f2bf_rne(acc[nt][r]);
            }
        }
    } else {
        // ---------------- sort pass 1 path (512 threads, 8 edges/thread) ----
        int* cnt   = (int*)smem;                    // NB_MAX ints
        int* off   = cnt + NB_MAX;                  // NB_MAX ints
        int* gbase = off + NB_MAX;                  // NB_MAX ints
        int* wsum  = gbase + NB_MAX;                // 16 ints
        unsigned int*   stag = (unsigned int*)(wsum + 16);      // CHUNK uints
        unsigned short* bkt  = (unsigned short*)(stag + CHUNK); // CHUNK ushorts

        const int bid = (int)blockIdx.x - gemmBlocks;
        const int e0  = bid * CHUNK;

        for (int i = t; i < nb; i += 512) cnt[i] = 0;
        __syncthreads();

        int myb[8]; int myr[8]; unsigned int myp[8];
#pragma unroll
        for (int l = 0; l < 8; ++l) {
            int e = e0 + l * 512 + t;
            if (e < E) {
                int s = src[e], d = dst[e];
                int b = s >> BKT_SHIFT;
                myb[l] = b;
                myp[l] = ((unsigned int)(s & (BKT_NODES - 1)) << 16) | (unsigned int)d;
                myr[l] = atomicAdd(&cnt[b], 1);
            } else myb[l] = -1;
        }
        __syncthreads();

        {
            int v    = (t < nb) ? cnt[t] : 0;
            int lane = t & 63, w = t >> 6;     // 8 waves
            int xv = v;
#pragma unroll
            for (int o = 1; o < 64; o <<= 1) {
                int y = __shfl_up(xv, o);
                if (lane >= o) xv += y;
            }
            if (lane == 63) wsum[w] = xv;
            __syncthreads();
            if (t == 0) {
                int s = 0;
#pragma unroll
                for (int k = 0; k < 8; ++k) { int tv = wsum[k]; wsum[k] = s; s += tv; }
                wsum[8] = s;
            }
            __syncthreads();
            int excl = xv - v + wsum[w];
            if (t < nb) off[t] = excl;
        }
        __syncthreads();

        for (int i = t; i < nb; i += 512) {
            int c = cnt[i];
            gbase[i] = c ? atomicAdd(&bucket_cursor[i], c) : 0;
        }
        __syncthreads();

#pragma unroll
        for (int l = 0; l < 8; ++l) {
            if (myb[l] >= 0) {
                int slot = off[myb[l]] + myr[l];
                stag[slot] = myp[l];
                bkt[slot]  = (unsigned short)myb[l];
            }
        }
        __syncthreads();

        const int tot = wsum[8];
        for (int slot = t; slot < tot; slot += 512) {
            int b   = bkt[slot];
            int pos = gbase[b] + (slot - off[b]);
            if (pos < BKT_CAP)
                bucket_buf[(size_t)b * BKT_CAP + pos] = stag[slot];
        }
    }
}

// ---------------------------------------------------------------------------
// Sort pass 2: one block (512 threads) per bucket; self-computed bucket base.
// ---------------------------------------------------------------------------
__global__ __launch_bounds__(512)
void sort_pass2(const unsigned int* __restrict__ bucket_buf,
                const int* __restrict__ bucket_cursor,
                int* __restrict__ row_start, int* __restrict__ dst_off,
                int n, int nb, int E)
{
    __shared__ int ncnt[BKT_NODES];
    __shared__ int noff[BKT_NODES];
    __shared__ int noffw[BKT_NODES];
    __shared__ int red[8];
    const int b = blockIdx.x;
    const int t = threadIdx.x;

    int partial = 0;
    for (int i = t; i < b; i += 512) partial += bucket_cursor[i];
#pragma unroll
    for (int o = 32; o; o >>= 1) partial += __shfl_xor(partial, o);
    if ((t & 63) == 0) red[t >> 6] = partial;
    __syncthreads();
    int base = 0;
#pragma unroll
    for (int k = 0; k < 8; ++k) base += red[k];

    int cntE = bucket_cursor[b];
    if (cntE > BKT_CAP) cntE = BKT_CAP;
    const unsigned int* bb = &bucket_buf[(size_t)b * BKT_CAP];

    if (t < BKT_NODES) ncnt[t] = 0;
    __syncthreads();
    for (int i = t; i < cntE; i += 512)
        atomicAdd(&ncnt[(bb[i] >> 16) & (BKT_NODES - 1)], 1);
    __syncthreads();

    if (t < 64) {
        int a0 = ncnt[2 * t], a1 = ncnt[2 * t + 1];
        int v = a0 + a1;
        int x = v;
#pragma unroll
        for (int o = 1; o < 64; o <<= 1) {
            int y = __shfl_up(x, o);
            if (t >= o) x += y;
        }
        int excl = x - v;
        noff[2 * t]      = excl;      noffw[2 * t]      = excl;
        noff[2 * t + 1]  = excl + a0; noffw[2 * t + 1]  = excl + a0;
    }
    __syncthreads();

    if (t < BKT_NODES) {
        int node = b * BKT_NODES + t;
        if (node < n) row_start[node] = base + noff[t];
    }
    if (b == 0 && t == 0) row_start[n] = E;

    for (int i = t; i < cntE; i += 512) {
        unsigned int p = bb[i];
        int sl  = (p >> 16) & (BKT_NODES - 1);
        int pos = atomicAdd(&noffw[sl], 1);
        dst_off[base + pos] = (int)(p & 0xFFFFu) << 7;   // d * 128
    }
}

// ---------------------------------------------------------------------------
// Fused single-pass edge kernel. Wave per node, 8 lanes/edge, 8 slots,
// 2 edges in flight; DPP + ds_swizzle reductions; rcp; __expf ELU.
// ---------------------------------------------------------------------------
__global__ __launch_bounds__(256)
void edge_fused(const unsigned short* __restrict__ WhC,
                const float* __restrict__ a,
                const int* __restrict__ row_start,
                const int* __restrict__ dst_off,
                float* __restrict__ out, int n)
{
    const int node = blockIdx.x * 4 + (threadIdx.x >> 6);
    if (node >= n) return;
    const int lane = threadIdx.x & 63;
    const int g    = lane >> 3;
    const int l8   = lane & 7;
    const int fo   = l8 * 8;

    const int beg = row_start[node];
    const int end = row_start[node + 1];

    f32x2 wsrc[4], av2[4];
    {
        uint4 raw = *(const uint4*)&WhC[(size_t)node * 128 + 64 + fo];
        const unsigned int u[4] = {raw.x, raw.y, raw.z, raw.w};
#pragma unroll
        for (int q = 0; q < 4; ++q) wsrc[q] = bf2_up(u[q]);
        float4 a0 = *(const float4*)&a[fo];
        float4 a1 = *(const float4*)&a[fo + 4];
        av2[0] = (f32x2){a0.x, a0.y}; av2[1] = (f32x2){a0.z, a0.w};
        av2[2] = (f32x2){a1.x, a1.y}; av2[3] = (f32x2){a1.z, a1.w};
    }

    float sumv = 0.f;
    f32x2 acc2[4];
#pragma unroll
    for (int q = 0; q < 4; ++q) acc2[q] = (f32x2){0.f, 0.f};

    int e = beg + g;
    for (; e + 8 < end; e += 16) {
        int d0 = dst_off[e];
        int d1 = dst_off[e + 8];
        uint4 rj0 = *(const uint4*)&WhC[(size_t)d0 + fo];
        uint4 rj1 = *(const uint4*)&WhC[(size_t)d1 + fo];
        uint4 ri0 = *(const uint4*)&WhC[(size_t)d0 + 64 + fo];
        uint4 ri1 = *(const uint4*)&WhC[(size_t)d1 + 64 + fo];
        const unsigned int uj0[4] = {rj0.x, rj0.y, rj0.z, rj0.w};
        const unsigned int uj1[4] = {rj1.x, rj1.y, rj1.z, rj1.w};
        f32x2 p0v = (f32x2){0.f, 0.f}, p1v = (f32x2){0.f, 0.f};
#pragma unroll
        for (int q = 0; q < 4; ++q) {
            f32x2 z0 = bf2_up(uj0[q]) + wsrc[q];
            f32x2 z1 = bf2_up(uj1[q]) + wsrc[q];
            f32x2 t0 = __builtin_elementwise_max(z0, z0 * ALPHA);
            f32x2 t1 = __builtin_elementwise_max(z1, z1 * ALPHA);
            p0v += av2[q] * t0;
            p1v += av2[q] * t1;
        }
        float p0 = p0v.x + p0v.y;
        float p1 = p1v.x + p1v.y;
        p0 = dpp_add<0xB1>(p0);  p1 = dpp_add<0xB1>(p1);   // xor1 (quad_perm)
        p0 = dpp_add<0x4E>(p0);  p1 = dpp_add<0x4E>(p1);   // xor2 (quad_perm)
        p0 = swz_add<4>(p0);     p1 = swz_add<4>(p1);      // xor4 (ds_swizzle)
        float ev0 = __expf(p0);
        float ev1 = __expf(p1);
        sumv += ev0 + ev1;
        const unsigned int ui0[4] = {ri0.x, ri0.y, ri0.z, ri0.w};
        const unsigned int ui1[4] = {ri1.x, ri1.y, ri1.z, ri1.w};
        f32x2 e0v = (f32x2){ev0, ev0};
        f32x2 e1v = (f32x2){ev1, ev1};
#pragma unroll
        for (int q = 0; q < 4; ++q) {
            acc2[q] += e0v * bf2_up(ui0[q]);
            acc2[q] += e1v * bf2_up(ui1[q]);
        }
    }
    if (e < end) {
        int d0 = dst_off[e];
        uint4 rj0 = *(const uint4*)&WhC[(size_t)d0 + fo];
        uint4 ri0 = *(const uint4*)&WhC[(size_t)d0 + 64 + fo];
        const unsigned int uj0[4] = {rj0.x, rj0.y, rj0.z, rj0.w};
        f32x2 p0v = (f32x2){0.f, 0.f};
#pragma unroll
        for (int q = 0; q < 4; ++q) {
            f32x2 z0 = bf2_up(uj0[q]) + wsrc[q];
            f32x2 t0 = __builtin_elementwise_max(z0, z0 * ALPHA);
            p0v += av2[q] * t0;
        }
        float p0 = p0v.x + p0v.y;
        p0 = dpp_add<0xB1>(p0);
        p0 = dpp_add<0x4E>(p0);
        p0 = swz_add<4>(p0);
        float ev0 = __expf(p0);
        sumv += ev0;
        const unsigned int ui0[4] = {ri0.x, ri0.y, ri0.z, ri0.w};
        f32x2 e0v = (f32x2){ev0, ev0};
#pragma unroll
        for (int q = 0; q < 4; ++q) acc2[q] += e0v * bf2_up(ui0[q]);
    }

    // merge the 8 groups: xor8 via row_ror:8 DPP, xor16 via ds_swizzle,
    // xor32 via shfl (crosses 32-lane halves).
    float acc[8];
#pragma unroll
    for (int q = 0; q < 4; ++q) { acc[2 * q] = acc2[q].x; acc[2 * q + 1] = acc2[q].y; }
    sumv = dpp_add<0x128>(sumv);
    sumv = swz_add<16>(sumv);
    sumv += __shfl_xor(sumv, 32);
#pragma unroll
    for (int j = 0; j < 8; ++j) {
        acc[j] = dpp_add<0x128>(acc[j]);
        acc[j] = swz_add<16>(acc[j]);
        acc[j] += __shfl_xor(acc[j], 32);
    }

    if (g == 0) {
        float rinv = __builtin_amdgcn_rcpf(sumv);
        float o[8];
#pragma unroll
        for (int j = 0; j < 8; ++j) {
            float v = acc[j] * rinv;
            o[j] = v > 0.f ? v : (__expf(v) - 1.0f);
        }
        float* op = &out[(size_t)node * OUT_F + fo];
        *(float4*)op       = make_float4(o[0], o[1], o[2], o[3]);
        *(float4*)(op + 4) = make_float4(o[4], o[5], o[6], o[7]);
    }
}

// ---------------------------------------------------------------------------
extern "C" void kernel_launch(void* const* d_in, const int* in_sizes, int n_in,
                              void* d_out, int out_size, void* d_ws, size_t ws_size,
                              hipStream_t stream)
{
    const float* x    = (const float*)d_in[0];
    const float* W    = (const float*)d_in[1];
    const float* a    = (const float*)d_in[2];
    const int*   edge = (const int*)d_in[3];

    const int n = in_sizes[0] / IN_F;      // 50000
    const int E = in_sizes[3] / 2;         // 800000
    const int* srcI = edge;
    const int* dstI = edge + E;
    const int nb = (n + BKT_NODES - 1) >> BKT_SHIFT;   // 391

    // workspace layout
    char* ws = (char*)d_ws;
    unsigned short* WhC = (unsigned short*)ws;  ws += (size_t)n * 128 * 2;
    unsigned short* Wt  = (unsigned short*)ws;  ws += (size_t)128 * IN_F * 2;
    unsigned int* bucket_buf = (unsigned int*)ws; ws += (size_t)nb * BKT_CAP * 4;
    int*   dst_off      = (int*)ws;             ws += (size_t)E * 4;
    int*   row_start    = (int*)ws;             ws += (size_t)(n + 1) * 4;
    int*   bucket_cursor= (int*)ws;             ws += (size_t)nb * 4;

    float* out = (float*)d_out;

    // 1) W transpose->bf16 (pre-swizzled) + bucket_cursor zeroing
    transpose_w<<<128, 256, 0, stream>>>(W, Wt, bucket_cursor, nb);

    // 2) fused GEMM (LDS-staged, 128 rows/block) + sort pass1
    int gblocks  = (n + 127) / 128;                  // 391
    int p1blocks = (E + CHUNK - 1) / CHUNK;          // 196
    gemm_sort<<<gblocks + p1blocks, 512, 0, stream>>>(
        x, Wt, WhC, srcI, dstI, bucket_cursor, bucket_buf, n, nb, E, gblocks);

    // 3) sort pass 2 (512 threads)
    sort_pass2<<<nb, 512, 0, stream>>>(bucket_buf, bucket_cursor,
                                       row_start, dst_off, n, nb, E);

    // 4) fused single-pass scores + exp + aggregate + ELU
    int ablocks = (n + 3) / 4;
    edge_fused<<<ablocks, 256, 0, stream>>>(WhC, a, row_start, dst_off, out, n);
}

// Round 18
// 63.706 us; speedup vs baseline: 1.2018x; 1.0333x over previous
//
#include <hip/hip_runtime.h>
#include <hip/hip_bf16.h>
#include <math.h>

#define IN_F   256
#define OUT_F  64
#define ALPHA  0.2f

// bucket sort params (requires n < 65536 so dst fits in 16 bits; n = 50000)
#define BKT_SHIFT 7
#define BKT_NODES 128
#define BKT_CAP   3072
#define NB_MAX    512
#define CHUNK     4096

typedef __attribute__((ext_vector_type(8))) short short8v;
typedef __attribute__((ext_vector_type(4))) float f32x4;
typedef __attribute__((ext_vector_type(2))) float f32x2;

static __device__ __forceinline__ unsigned short f2bf_rne(float f) {
    unsigned int u = __float_as_uint(f);
    unsigned int lsb = (u >> 16) & 1u;
    u += 0x7FFFu + lsb;
    return (unsigned short)(u >> 16);
}

static __device__ __forceinline__ unsigned int pack_bf2(float lo, float hi) {
    __hip_bfloat162 h = __float22bfloat162_rn(float2{lo, hi});
    return *reinterpret_cast<unsigned int*>(&h);
}

// swizzled Wt index: element (nc, k) lives at nc*256 + (k ^ ((nc&7)<<3))
static __device__ __forceinline__ int wt_idx(int nc, int k) {
    return nc * IN_F + (k ^ ((nc & 7) << 3));
}

// unpack 2 packed bf16 -> f32x2 {lo, hi}
static __device__ __forceinline__ f32x2 bf2_up(unsigned int u) {
    f32x2 r;
    r.x = __uint_as_float(u << 16);
    r.y = __uint_as_float(u & 0xFFFF0000u);
    return r;
}

// DPP cross-lane adds (VALU pipe). CTRL compile-time.
// xor1: quad_perm [1,0,3,2]=0xB1 ; xor2: quad_perm [2,3,0,1]=0x4E ;
// xor8 within 16-lane row: row_ror:8 = 0x128.
template<int CTRL>
static __device__ __forceinline__ float dpp_add(float x) {
    int y = __builtin_amdgcn_update_dpp(0, __float_as_int(x), CTRL, 0xF, 0xF, true);
    return x + __int_as_float(y);
}

// ds_swizzle xor-add (single DS instr, 32-lane local; MASK<=31).
// BitMode offset = xor<<10 | or<<5 | and(0x1F).
template<int MASK>
static __device__ __forceinline__ float swz_add(float x) {
    int y = __builtin_amdgcn_ds_swizzle(__float_as_int(x), (MASK << 10) | 0x1F);
    return x + __int_as_float(y);
}

// ---------------------------------------------------------------------------
// Wt (swizzled) bf16; block 0 also zeroes bucket_cursor (replaces memset).
// ---------------------------------------------------------------------------
__global__ __launch_bounds__(256)
void transpose_w(const float* __restrict__ W, unsigned short* __restrict__ Wt,
                 int* __restrict__ bucket_cursor, int nb)
{
    if (blockIdx.x == 0) {
        for (int i = threadIdx.x; i < nb; i += 256) bucket_cursor[i] = 0;
    }
    int tid = blockIdx.x * 256 + threadIdx.x;   // 0..32767
    int nc = tid >> 8;
    int k  = tid & 255;
    float v = (nc < 64) ? W[(size_t)k * OUT_F + nc]
                        : W[(size_t)(IN_F + k) * OUT_F + (nc - 64)];
    Wt[wt_idx(nc, k)] = f2bf_rne(v);
}

// ---------------------------------------------------------------------------
// Fused independent phases, block-partitioned:
//   blocks [0, gemmBlocks):       MFMA GEMM, Wt staged to 64KB LDS (the
//     LDS broadcast is essential: L2-serving regressed 19->54 us, round 14)
//   blocks [gemmBlocks, total):   sort pass1 -> bucket binning of edges
// ---------------------------------------------------------------------------
__global__ __launch_bounds__(512)
void gemm_sort(const float* __restrict__ x, const unsigned short* __restrict__ Wt,
               unsigned short* __restrict__ WhC,
               const int* __restrict__ src, const int* __restrict__ dst,
               int* __restrict__ bucket_cursor, unsigned int* __restrict__ bucket_buf,
               int n, int nb, int E, int gemmBlocks)
{
    __shared__ __align__(16) unsigned char smem[65536];
    const int t = threadIdx.x;

    if ((int)blockIdx.x < gemmBlocks) {
        // ---------------- GEMM path (LDS-staged B) ----------------
        unsigned short* lds_wt = (unsigned short*)smem;
        const int wid  = t >> 6;
        const int lane = t & 63;
        const int r16  = lane & 15;
        const int kq   = lane >> 4;
        const int m0   = blockIdx.x * 128 + wid * 16;

        {
            const uint4* gw = (const uint4*)Wt;
            uint4*       lw = (uint4*)lds_wt;
#pragma unroll
            for (int i = 0; i < 8; ++i)
                lw[t + i * 512] = gw[t + i * 512];
        }

        int arow = m0 + r16;
        if (arow >= n) arow = n - 1;
        const float* xr = &x[(size_t)arow * IN_F + kq * 8];

        float4 araw[16];
#pragma unroll
        for (int ks = 0; ks < 8; ++ks) {
            araw[2 * ks]     = *(const float4*)&xr[ks * 32];
            araw[2 * ks + 1] = *(const float4*)&xr[ks * 32 + 4];
        }
        __syncthreads();

        short8v afrag[8];
#pragma unroll
        for (int ks = 0; ks < 8; ++ks) {
            union { short8v s; unsigned int u[4]; } fr;
            fr.u[0] = pack_bf2(araw[2 * ks].x, araw[2 * ks].y);
            fr.u[1] = pack_bf2(araw[2 * ks].z, araw[2 * ks].w);
            fr.u[2] = pack_bf2(araw[2 * ks + 1].x, araw[2 * ks + 1].y);
            fr.u[3] = pack_bf2(araw[2 * ks + 1].z, araw[2 * ks + 1].w);
            afrag[ks] = fr.s;
        }

        f32x4 acc[8];
#pragma unroll
        for (int nt = 0; nt < 8; ++nt) acc[nt] = (f32x4){0.f, 0.f, 0.f, 0.f};

#pragma unroll
        for (int ks = 0; ks < 8; ++ks) {
#pragma unroll
            for (int nt = 0; nt < 8; ++nt) {
                int nc = nt * 16 + r16;
                short8v b = *(const short8v*)&lds_wt[wt_idx(nc, ks * 32 + kq * 8)];
                acc[nt] = __builtin_amdgcn_mfma_f32_16x16x32_bf16(afrag[ks], b, acc[nt], 0, 0, 0);
            }
        }

        const int rbase = m0 + kq * 4;
#pragma unroll
        for (int nt = 0; nt < 8; ++nt) {
            int colc = nt * 16 + r16;
            int off  = (colc < 64) ? (colc + 64) : (colc - 64);
#pragma unroll
            for (int r = 0; r < 4; ++r) {
                int gr = rbase + r;
                if (gr < n) WhC[(size_t)gr * 128 + off] = f2bf_rne(acc[nt][r]);
            }
        }
    } else {
        // ---------------- sort pass 1 path (512 threads, 8 edges/thread) ----
        int* cnt   = (int*)smem;                    // NB_MAX ints
        int* off   = cnt + NB_MAX;                  // NB_MAX ints
        int* gbase = off + NB_MAX;                  // NB_MAX ints
        int* wsum  = gbase + NB_MAX;                // 16 ints
        unsigned int*   stag = (unsigned int*)(wsum + 16);      // CHUNK uints
        unsigned short* bkt  = (unsigned short*)(stag + CHUNK); // CHUNK ushorts

        const int bid = (int)blockIdx.x - gemmBlocks;
        const int e0  = bid * CHUNK;

        for (int i = t; i < nb; i += 512) cnt[i] = 0;
        __syncthreads();

        int myb[8]; int myr[8]; unsigned int myp[8];
#pragma unroll
        for (int l = 0; l < 8; ++l) {
            int e = e0 + l * 512 + t;
            if (e < E) {
                int s = src[e], d = dst[e];
                int b = s >> BKT_SHIFT;
                myb[l] = b;
                myp[l] = ((unsigned int)(s & (BKT_NODES - 1)) << 16) | (unsigned int)d;
                myr[l] = atomicAdd(&cnt[b], 1);
            } else myb[l] = -1;
        }
        __syncthreads();

        {
            int v    = (t < nb) ? cnt[t] : 0;
            int lane = t & 63, w = t >> 6;     // 8 waves
            int xv = v;
#pragma unroll
            for (int o = 1; o < 64; o <<= 1) {
                int y = __shfl_up(xv, o);
                if (lane >= o) xv += y;
            }
            if (lane == 63) wsum[w] = xv;
            __syncthreads();
            if (t == 0) {
                int s = 0;
#pragma unroll
                for (int k = 0; k < 8; ++k) { int tv = wsum[k]; wsum[k] = s; s += tv; }
                wsum[8] = s;
            }
            __syncthreads();
            int excl = xv - v + wsum[w];
            if (t < nb) off[t] = excl;
        }
        __syncthreads();

        for (int i = t; i < nb; i += 512) {
            int c = cnt[i];
            gbase[i] = c ? atomicAdd(&bucket_cursor[i], c) : 0;
        }
        __syncthreads();

#pragma unroll
        for (int l = 0; l < 8; ++l) {
            if (myb[l] >= 0) {
                int slot = off[myb[l]] + myr[l];
                stag[slot] = myp[l];
                bkt[slot]  = (unsigned short)myb[l];
            }
        }
        __syncthreads();

        const int tot = wsum[8];
        for (int slot = t; slot < tot; slot += 512) {
            int b   = bkt[slot];
            int pos = gbase[b] + (slot - off[b]);
            if (pos < BKT_CAP)
                bucket_buf[(size_t)b * BKT_CAP + pos] = stag[slot];
        }
    }
}

// ---------------------------------------------------------------------------
// Sort pass 2: one block (512 threads) per bucket; self-computed bucket base.
// ---------------------------------------------------------------------------
__global__ __launch_bounds__(512)
void sort_pass2(const unsigned int* __restrict__ bucket_buf,
                const int* __restrict__ bucket_cursor,
                int* __restrict__ row_start, int* __restrict__ dst_off,
                int n, int nb, int E)
{
    __shared__ int ncnt[BKT_NODES];
    __shared__ int noff[BKT_NODES];
    __shared__ int noffw[BKT_NODES];
    __shared__ int red[8];
    const int b = blockIdx.x;
    const int t = threadIdx.x;

    int partial = 0;
    for (int i = t; i < b; i += 512) partial += bucket_cursor[i];
#pragma unroll
    for (int o = 32; o; o >>= 1) partial += __shfl_xor(partial, o);
    if ((t & 63) == 0) red[t >> 6] = partial;
    __syncthreads();
    int base = 0;
#pragma unroll
    for (int k = 0; k < 8; ++k) base += red[k];

    int cntE = bucket_cursor[b];
    if (cntE > BKT_CAP) cntE = BKT_CAP;
    const unsigned int* bb = &bucket_buf[(size_t)b * BKT_CAP];

    if (t < BKT_NODES) ncnt[t] = 0;
    __syncthreads();
    for (int i = t; i < cntE; i += 512)
        atomicAdd(&ncnt[(bb[i] >> 16) & (BKT_NODES - 1)], 1);
    __syncthreads();

    if (t < 64) {
        int a0 = ncnt[2 * t], a1 = ncnt[2 * t + 1];
        int v = a0 + a1;
        int x = v;
#pragma unroll
        for (int o = 1; o < 64; o <<= 1) {
            int y = __shfl_up(x, o);
            if (t >= o) x += y;
        }
        int excl = x - v;
        noff[2 * t]      = excl;      noffw[2 * t]      = excl;
        noff[2 * t + 1]  = excl + a0; noffw[2 * t + 1]  = excl + a0;
    }
    __syncthreads();

    if (t < BKT_NODES) {
        int node = b * BKT_NODES + t;
        if (node < n) row_start[node] = base + noff[t];
    }
    if (b == 0 && t == 0) row_start[n] = E;

    for (int i = t; i < cntE; i += 512) {
        unsigned int p = bb[i];
        int sl  = (p >> 16) & (BKT_NODES - 1);
        int pos = atomicAdd(&noffw[sl], 1);
        dst_off[base + pos] = (int)(p & 0xFFFFu) << 7;   // d * 128
    }
}

// ---------------------------------------------------------------------------
// Fused single-pass edge kernel. TWO nodes per wave (32 lanes each); per node
// 4 groups x 8 lanes, 2 edges in flight per group. Merge tree: xor8 (DPP) +
// xor16 (ds_swizzle) only — no cross-half reduction needed. rcp; __expf ELU.
// ---------------------------------------------------------------------------
__global__ __launch_bounds__(256)
void edge_fused(const unsigned short* __restrict__ WhC,
                const float* __restrict__ a,
                const int* __restrict__ row_start,
                const int* __restrict__ dst_off,
                float* __restrict__ out, int n)
{
    const int lane = threadIdx.x & 63;
    const int wid  = threadIdx.x >> 6;
    const int h    = lane >> 5;                        // node half 0/1
    const int node = blockIdx.x * 8 + wid * 2 + h;
    if (node >= n) return;
    const int g    = (lane >> 3) & 3;                  // group within half
    const int l8   = lane & 7;
    const int fo   = l8 * 8;

    const int beg = row_start[node];
    const int end = row_start[node + 1];

    f32x2 wsrc[4], av2[4];
    {
        uint4 raw = *(const uint4*)&WhC[(size_t)node * 128 + 64 + fo];
        const unsigned int u[4] = {raw.x, raw.y, raw.z, raw.w};
#pragma unroll
        for (int q = 0; q < 4; ++q) wsrc[q] = bf2_up(u[q]);
        float4 a0 = *(const float4*)&a[fo];
        float4 a1 = *(const float4*)&a[fo + 4];
        av2[0] = (f32x2){a0.x, a0.y}; av2[1] = (f32x2){a0.z, a0.w};
        av2[2] = (f32x2){a1.x, a1.y}; av2[3] = (f32x2){a1.z, a1.w};
    }

    float sumv = 0.f;
    f32x2 acc2[4];
#pragma unroll
    for (int q = 0; q < 4; ++q) acc2[q] = (f32x2){0.f, 0.f};

    int e = beg + g;
    for (; e + 4 < end; e += 8) {
        int d0 = dst_off[e];
        int d1 = dst_off[e + 4];
        uint4 rj0 = *(const uint4*)&WhC[(size_t)d0 + fo];
        uint4 rj1 = *(const uint4*)&WhC[(size_t)d1 + fo];
        uint4 ri0 = *(const uint4*)&WhC[(size_t)d0 + 64 + fo];
        uint4 ri1 = *(const uint4*)&WhC[(size_t)d1 + 64 + fo];
        const unsigned int uj0[4] = {rj0.x, rj0.y, rj0.z, rj0.w};
        const unsigned int uj1[4] = {rj1.x, rj1.y, rj1.z, rj1.w};
        f32x2 p0v = (f32x2){0.f, 0.f}, p1v = (f32x2){0.f, 0.f};
#pragma unroll
        for (int q = 0; q < 4; ++q) {
            f32x2 z0 = bf2_up(uj0[q]) + wsrc[q];
            f32x2 z1 = bf2_up(uj1[q]) + wsrc[q];
            f32x2 t0 = __builtin_elementwise_max(z0, z0 * ALPHA);
            f32x2 t1 = __builtin_elementwise_max(z1, z1 * ALPHA);
            p0v += av2[q] * t0;
            p1v += av2[q] * t1;
        }
        float p0 = p0v.x + p0v.y;
        float p1 = p1v.x + p1v.y;
        p0 = dpp_add<0xB1>(p0);  p1 = dpp_add<0xB1>(p1);   // xor1
        p0 = dpp_add<0x4E>(p0);  p1 = dpp_add<0x4E>(p1);   // xor2
        p0 = swz_add<4>(p0);     p1 = swz_add<4>(p1);      // xor4
        float ev0 = __expf(p0);
        float ev1 = __expf(p1);
        sumv += ev0 + ev1;
        const unsigned int ui0[4] = {ri0.x, ri0.y, ri0.z, ri0.w};
        const unsigned int ui1[4] = {ri1.x, ri1.y, ri1.z, ri1.w};
        f32x2 e0v = (f32x2){ev0, ev0};
        f32x2 e1v = (f32x2){ev1, ev1};
#pragma unroll
        for (int q = 0; q < 4; ++q) {
            acc2[q] += e0v * bf2_up(ui0[q]);
            acc2[q] += e1v * bf2_up(ui1[q]);
        }
    }
    if (e < end) {
        int d0 = dst_off[e];
        uint4 rj0 = *(const uint4*)&WhC[(size_t)d0 + fo];
        uint4 ri0 = *(const uint4*)&WhC[(size_t)d0 + 64 + fo];
        const unsigned int uj0[4] = {rj0.x, rj0.y, rj0.z, rj0.w};
        f32x2 p0v = (f32x2){0.f, 0.f};
#pragma unroll
        for (int q = 0; q < 4; ++q) {
            f32x2 z0 = bf2_up(uj0[q]) + wsrc[q];
            f32x2 t0 = __builtin_elementwise_max(z0, z0 * ALPHA);
            p0v += av2[q] * t0;
        }
        float p0 = p0v.x + p0v.y;
        p0 = dpp_add<0xB1>(p0);
        p0 = dpp_add<0x4E>(p0);
        p0 = swz_add<4>(p0);
        float ev0 = __expf(p0);
        sumv += ev0;
        const unsigned int ui0[4] = {ri0.x, ri0.y, ri0.z, ri0.w};
        f32x2 e0v = (f32x2){ev0, ev0};
#pragma unroll
        for (int q = 0; q < 4; ++q) acc2[q] += e0v * bf2_up(ui0[q]);
    }

    // merge the 4 groups of this half: xor8 (row_ror:8 DPP, within 16-rows)
    // then xor16 (ds_swizzle, within this 32-lane half). No xor32 needed.
    float acc[8];
#pragma unroll
    for (int q = 0; q < 4; ++q) { acc[2 * q] = acc2[q].x; acc[2 * q + 1] = acc2[q].y; }
    sumv = dpp_add<0x128>(sumv);
    sumv = swz_add<16>(sumv);
#pragma unroll
    for (int j = 0; j < 8; ++j) {
        acc[j] = dpp_add<0x128>(acc[j]);
        acc[j] = swz_add<16>(acc[j]);
    }

    if (g == 0) {
        float rinv = __builtin_amdgcn_rcpf(sumv);
        float o[8];
#pragma unroll
        for (int j = 0; j < 8; ++j) {
            float v = acc[j] * rinv;
            o[j] = v > 0.f ? v : (__expf(v) - 1.0f);
        }
        float* op = &out[(size_t)node * OUT_F + fo];
        *(float4*)op       = make_float4(o[0], o[1], o[2], o[3]);
        *(float4*)(op + 4) = make_float4(o[4], o[5], o[6], o[7]);
    }
}

// ---------------------------------------------------------------------------
extern "C" void kernel_launch(void* const* d_in, const int* in_sizes, int n_in,
                              void* d_out, int out_size, void* d_ws, size_t ws_size,
                              hipStream_t stream)
{
    const float* x    = (const float*)d_in[0];
    const float* W    = (const float*)d_in[1];
    const float* a    = (const float*)d_in[2];
    const int*   edge = (const int*)d_in[3];

    const int n = in_sizes[0] / IN_F;      // 50000
    const int E = in_sizes[3] / 2;         // 800000
    const int* srcI = edge;
    const int* dstI = edge + E;
    const int nb = (n + BKT_NODES - 1) >> BKT_SHIFT;   // 391

    // workspace layout
    char* ws = (char*)d_ws;
    unsigned short* WhC = (unsigned short*)ws;  ws += (size_t)n * 128 * 2;
    unsigned short* Wt  = (unsigned short*)ws;  ws += (size_t)128 * IN_F * 2;
    unsigned int* bucket_buf = (unsigned int*)ws; ws += (size_t)nb * BKT_CAP * 4;
    int*   dst_off      = (int*)ws;             ws += (size_t)E * 4;
    int*   row_start    = (int*)ws;             ws += (size_t)(n + 1) * 4;
    int*   bucket_cursor= (int*)ws;             ws += (size_t)nb * 4;

    float* out = (float*)d_out;

    // 1) W transpose->bf16 (pre-swizzled) + bucket_cursor zeroing
    transpose_w<<<128, 256, 0, stream>>>(W, Wt, bucket_cursor, nb);

    // 2) fused GEMM (LDS-staged, 128 rows/block) + sort pass1
    int gblocks  = (n + 127) / 128;                  // 391
    int p1blocks = (E + CHUNK - 1) / CHUNK;          // 196
    gemm_sort<<<gblocks + p1blocks, 512, 0, stream>>>(
        x, Wt, WhC, srcI, dstI, bucket_cursor, bucket_buf, n, nb, E, gblocks);

    // 3) sort pass 2 (512 threads)
    sort_pass2<<<nb, 512, 0, stream>>>(bucket_buf, bucket_cursor,
                                       row_start, dst_off, n, nb, E);

    // 4) fused single-pass scores + exp + aggregate + ELU (2 nodes/wave)
    int ablocks = (n + 7) / 8;
    edge_fused<<<ablocks, 256, 0, stream>>>(WhC, a, row_start, dst_off, out, n);
}